// Round 2
// baseline (356.238 us; speedup 1.0000x reference)
//
#include <hip/hip_runtime.h>

typedef __attribute__((ext_vector_type(8))) short short8;
typedef __attribute__((ext_vector_type(4))) float f32x4;
typedef __attribute__((ext_vector_type(4))) int i32x4;
typedef __attribute__((ext_vector_type(4))) unsigned short u16x4;

#define B_  4
#define N_  2048
#define D_  512
#define H_  8
#define DH_ 64
#define M_  (B_ * N_)   // 8192

__device__ __forceinline__ float bf2f(unsigned short s) {
    union { unsigned u; float f; } un; un.u = ((unsigned)s) << 16; return un.f;
}
__device__ __forceinline__ unsigned short f2bf(float f) {
    union { float f; unsigned u; } un; un.f = f;
    unsigned r = un.u + 0x7FFFu + ((un.u >> 16) & 1u);
    return (unsigned short)(r >> 16);
}

// ---------------------------------------------------------------------------
// fp32 -> bf16 conversion (vectorized, 4 elems/thread)
// ---------------------------------------------------------------------------
__global__ __launch_bounds__(256) void cvt_x(const float* __restrict__ src,
                                             unsigned short* __restrict__ dst) {
    const int i = (blockIdx.x * 256 + threadIdx.x) * 4;
    f32x4 v = *(const f32x4*)(src + i);
    u16x4 o;
    o[0] = f2bf(v[0]); o[1] = f2bf(v[1]); o[2] = f2bf(v[2]); o[3] = f2bf(v[3]);
    *(u16x4*)(dst + i) = o;
}

__global__ __launch_bounds__(256) void cvt_w(const float* __restrict__ W0,
                                             const float* __restrict__ W1,
                                             const float* __restrict__ W2,
                                             const float* __restrict__ W3,
                                             unsigned short* __restrict__ dst) {
    const int sel = blockIdx.y;
    const float* src = (sel == 0) ? W0 : (sel == 1) ? W1 : (sel == 2) ? W2 : W3;
    unsigned short* d = dst + (size_t)sel * D_ * D_;
    const int i = (blockIdx.x * 256 + threadIdx.x) * 4;
    f32x4 v = *(const f32x4*)(src + i);
    u16x4 o;
    o[0] = f2bf(v[0]); o[1] = f2bf(v[1]); o[2] = f2bf(v[2]); o[3] = f2bf(v[3]);
    *(u16x4*)(d + i) = o;
}

// ---------------------------------------------------------------------------
// NT GEMM: out[m][n] = sum_k A[m][k] * W[n][k] + bias[n]
// A: [8192][512] bf16. W select via blockIdx.y>>2, each 512x512 bf16.
// Tile 128x128, BK=32, 4 waves, 16x16x32 bf16 MFMA.
// F32OUT: write fp32 to outf instead of bf16 to outb.
// ---------------------------------------------------------------------------
template <bool F32OUT>
__global__ __launch_bounds__(256) void gemm_nt(
    const unsigned short* __restrict__ A,
    const unsigned short* __restrict__ W,     // [nsel][512][512]
    const float* __restrict__ Bv0,
    const float* __restrict__ Bv1,
    const float* __restrict__ Bv2,
    unsigned short* __restrict__ outb,
    float* __restrict__ outf)
{
    const int mt = blockIdx.x;
    const int nt = blockIdx.y;
    const int sel = nt >> 2;
    const unsigned short* Wp = W + (size_t)sel * D_ * D_;
    const float* Bv = (sel == 0) ? Bv0 : (sel == 1) ? Bv1 : Bv2;
    const int n0 = (nt & 3) * 128;

    __shared__ __align__(16) unsigned short As[128][48];
    __shared__ __align__(16) unsigned short Bs[128][48];

    const int tid = threadIdx.x;
    const int w   = tid >> 6;
    const int l   = tid & 63;
    const int l15 = l & 15;
    const int qd  = l >> 4;
    const int wr  = w >> 1;
    const int wc  = w & 1;

    f32x4 acc[4][4];
#pragma unroll
    for (int i = 0; i < 4; ++i)
#pragma unroll
        for (int j = 0; j < 4; ++j)
            acc[i][j] = (f32x4){0.f, 0.f, 0.f, 0.f};

    const int c0 = tid, c1 = tid + 256;
    const int r0 = c0 >> 2, o0 = (c0 & 3) << 3;
    const int r1 = c1 >> 2, o1 = (c1 & 3) << 3;

    for (int k0 = 0; k0 < D_; k0 += 32) {
        __syncthreads();
        *(i32x4*)&As[r0][o0] = *(const i32x4*)(A  + (size_t)(mt * 128 + r0) * D_ + k0 + o0);
        *(i32x4*)&Bs[r0][o0] = *(const i32x4*)(Wp + (size_t)(n0 + r0) * D_ + k0 + o0);
        *(i32x4*)&As[r1][o1] = *(const i32x4*)(A  + (size_t)(mt * 128 + r1) * D_ + k0 + o1);
        *(i32x4*)&Bs[r1][o1] = *(const i32x4*)(Wp + (size_t)(n0 + r1) * D_ + k0 + o1);
        __syncthreads();

        short8 af[4], bf[4];
#pragma unroll
        for (int rt = 0; rt < 4; ++rt)
            af[rt] = *(const short8*)&As[wr * 64 + rt * 16 + l15][qd * 8];
#pragma unroll
        for (int ct = 0; ct < 4; ++ct)
            bf[ct] = *(const short8*)&Bs[wc * 64 + ct * 16 + l15][qd * 8];
#pragma unroll
        for (int rt = 0; rt < 4; ++rt)
#pragma unroll
            for (int ct = 0; ct < 4; ++ct)
                acc[rt][ct] = __builtin_amdgcn_mfma_f32_16x16x32_bf16(
                    af[rt], bf[ct], acc[rt][ct], 0, 0, 0);
    }

#pragma unroll
    for (int ct = 0; ct < 4; ++ct) {
        const int col = n0 + wc * 64 + ct * 16 + l15;
        const float bias = Bv[col];
#pragma unroll
        for (int rt = 0; rt < 4; ++rt) {
            const int row0 = mt * 128 + wr * 64 + rt * 16 + qd * 4;
#pragma unroll
            for (int r = 0; r < 4; ++r) {
                const size_t oidx = (size_t)(row0 + r) * D_ + col;
                if (F32OUT) outf[oidx] = acc[rt][ct][r] + bias;
                else        outb[(size_t)sel * M_ * D_ + oidx] = f2bf(acc[rt][ct][r] + bias);
            }
        }
    }
}

// ---------------------------------------------------------------------------
// In-place per-head LayerNorm over DH=64 on Yq and Yk (bf16 data, fp32 params)
// ---------------------------------------------------------------------------
__global__ __launch_bounds__(256) void ln_qk(
    unsigned short* __restrict__ Yq,
    unsigned short* __restrict__ Yk,
    const float* __restrict__ qg, const float* __restrict__ qb,
    const float* __restrict__ kg, const float* __restrict__ kb)
{
    const int id = blockIdx.x * 4 + (threadIdx.x >> 6);  // m*8 + h
    const int i  = threadIdx.x & 63;
    const int m  = id >> 3;
    const int h  = id & 7;
    const size_t idx = (size_t)m * D_ + h * DH_ + i;

    {
        float x = bf2f(Yq[idx]);
        float s = x, s2 = x * x;
#pragma unroll
        for (int o = 32; o; o >>= 1) { s += __shfl_xor(s, o); s2 += __shfl_xor(s2, o); }
        float mu = s * 0.015625f;
        float var = s2 * 0.015625f - mu * mu;
        float rs = rsqrtf(var + 1e-6f);
        Yq[idx] = f2bf((x - mu) * rs * qg[i] + qb[i]);
    }
    {
        float x = bf2f(Yk[idx]);
        float s = x, s2 = x * x;
#pragma unroll
        for (int o = 32; o; o >>= 1) { s += __shfl_xor(s, o); s2 += __shfl_xor(s2, o); }
        float mu = s * 0.015625f;
        float var = s2 * 0.015625f - mu * mu;
        float rs = rsqrtf(var + 1e-6f);
        Yk[idx] = f2bf((x - mu) * rs * kg[i] + kb[i]);
    }
}

// ---------------------------------------------------------------------------
// Flash attention: per block 64 q-rows of one (b,h); 4 waves x 16 rows.
// bias read as fp32 directly from input.
// ---------------------------------------------------------------------------
__global__ __launch_bounds__(256) void attn_kernel(
    const unsigned short* __restrict__ Q,
    const unsigned short* __restrict__ Kp,
    const unsigned short* __restrict__ Vp,
    const float* __restrict__ bias,
    unsigned short* __restrict__ AO)
{
    const int h  = blockIdx.x;
    const int qt = blockIdx.y;
    const int b  = blockIdx.z;

    const int tid = threadIdx.x;
    const int w   = tid >> 6;
    const int l   = tid & 63;
    const int l15 = l & 15;
    const int qd  = l >> 4;

    __shared__ __align__(16) unsigned short Ks[64][72];
    __shared__ __align__(16) unsigned short Vs[64][72];   // [dh][kv]
    __shared__ __align__(16) unsigned short Ps[4][16][72];

    const int qrow0 = qt * 64 + w * 16;
    const unsigned short* qptr = Q + (size_t)(b * N_ + qrow0 + l15) * D_ + h * DH_;
    const short8 qf0 = *(const short8*)(qptr + qd * 8);
    const short8 qf1 = *(const short8*)(qptr + 32 + qd * 8);

    const unsigned short* kbase = Kp + (size_t)b * N_ * D_ + h * DH_;
    const unsigned short* vbase = Vp + (size_t)b * N_ * D_ + h * DH_;

    size_t biasrow[4];
#pragma unroll
    for (int r = 0; r < 4; ++r)
        biasrow[r] = ((size_t)b * N_ + qrow0 + qd * 4 + r) * (size_t)N_ + l15;

    f32x4 Of[4];
#pragma unroll
    for (int ct = 0; ct < 4; ++ct) Of[ct] = (f32x4){0.f, 0.f, 0.f, 0.f};
    float m_i[4] = {-1e30f, -1e30f, -1e30f, -1e30f};
    float l_i[4] = {0.f, 0.f, 0.f, 0.f};

    for (int kt = 0; kt < N_ / 64; ++kt) {
        const int kv0 = kt * 64;
        __syncthreads();
#pragma unroll
        for (int c = tid; c < 512; c += 256) {
            const int kvr = c >> 3;
            const int c8  = (c & 7) << 3;
            *(i32x4*)&Ks[kvr][c8] =
                *(const i32x4*)(kbase + (size_t)(kv0 + kvr) * D_ + c8);
            short8 v8 = *(const short8*)(vbase + (size_t)(kv0 + kvr) * D_ + c8);
#pragma unroll
            for (int j = 0; j < 8; ++j) Vs[c8 + j][kvr] = (unsigned short)v8[j];
        }
        __syncthreads();

        f32x4 Sf[4];
#pragma unroll
        for (int ct = 0; ct < 4; ++ct) {
            const short8 kb0 = *(const short8*)&Ks[ct * 16 + l15][qd * 8];
            const short8 kb1 = *(const short8*)&Ks[ct * 16 + l15][32 + qd * 8];
            f32x4 s = (f32x4){0.f, 0.f, 0.f, 0.f};
            s = __builtin_amdgcn_mfma_f32_16x16x32_bf16(qf0, kb0, s, 0, 0, 0);
            s = __builtin_amdgcn_mfma_f32_16x16x32_bf16(qf1, kb1, s, 0, 0, 0);
            Sf[ct] = s;
        }

#pragma unroll
        for (int r = 0; r < 4; ++r) {
            float sv[4];
            float mx = -1e30f;
#pragma unroll
            for (int ct = 0; ct < 4; ++ct) {
                float sval = Sf[ct][r] * 0.125f + bias[biasrow[r] + kv0 + ct * 16];
                sv[ct] = sval;
                mx = fmaxf(mx, sval);
            }
            mx = fmaxf(mx, __shfl_xor(mx, 1));
            mx = fmaxf(mx, __shfl_xor(mx, 2));
            mx = fmaxf(mx, __shfl_xor(mx, 4));
            mx = fmaxf(mx, __shfl_xor(mx, 8));
            const float mnew  = fmaxf(m_i[r], mx);
            const float alpha = __expf(m_i[r] - mnew);
            float rsum = 0.f;
#pragma unroll
            for (int ct = 0; ct < 4; ++ct) {
                float p = __expf(sv[ct] - mnew);
                rsum += p;
                Ps[w][qd * 4 + r][ct * 16 + l15] = f2bf(p);
            }
            rsum += __shfl_xor(rsum, 1);
            rsum += __shfl_xor(rsum, 2);
            rsum += __shfl_xor(rsum, 4);
            rsum += __shfl_xor(rsum, 8);
            l_i[r] = l_i[r] * alpha + rsum;
            m_i[r] = mnew;
#pragma unroll
            for (int ct = 0; ct < 4; ++ct) Of[ct][r] = Of[ct][r] * alpha;
        }
        __syncthreads();

        const short8 pa0 = *(const short8*)&Ps[w][l15][qd * 8];
        const short8 pa1 = *(const short8*)&Ps[w][l15][32 + qd * 8];
#pragma unroll
        for (int ct = 0; ct < 4; ++ct) {
            const short8 vb0 = *(const short8*)&Vs[ct * 16 + l15][qd * 8];
            const short8 vb1 = *(const short8*)&Vs[ct * 16 + l15][32 + qd * 8];
            Of[ct] = __builtin_amdgcn_mfma_f32_16x16x32_bf16(pa0, vb0, Of[ct], 0, 0, 0);
            Of[ct] = __builtin_amdgcn_mfma_f32_16x16x32_bf16(pa1, vb1, Of[ct], 0, 0, 0);
        }
    }

#pragma unroll
    for (int ct = 0; ct < 4; ++ct) {
        const float inv0 = 1.f / l_i[0];
        const float inv1 = 1.f / l_i[1];
        const float inv2 = 1.f / l_i[2];
        const float inv3 = 1.f / l_i[3];
        const int col = h * DH_ + ct * 16 + l15;
        AO[(size_t)(b * N_ + qrow0 + qd * 4 + 0) * D_ + col] = f2bf(Of[ct][0] * inv0);
        AO[(size_t)(b * N_ + qrow0 + qd * 4 + 1) * D_ + col] = f2bf(Of[ct][1] * inv1);
        AO[(size_t)(b * N_ + qrow0 + qd * 4 + 2) * D_ + col] = f2bf(Of[ct][2] * inv2);
        AO[(size_t)(b * N_ + qrow0 + qd * 4 + 3) * D_ + col] = f2bf(Of[ct][3] * inv3);
    }
}

// ---------------------------------------------------------------------------
extern "C" void kernel_launch(void* const* d_in, const int* in_sizes, int n_in,
                              void* d_out, int out_size, void* d_ws, size_t ws_size,
                              hipStream_t stream) {
    const float* x  = (const float*)d_in[0];
    const float* ab = (const float*)d_in[1];
    const float* Wq = (const float*)d_in[2];
    const float* bq = (const float*)d_in[3];
    const float* Wk = (const float*)d_in[4];
    const float* bk = (const float*)d_in[5];
    const float* Wv = (const float*)d_in[6];
    const float* bv = (const float*)d_in[7];
    const float* Wo = (const float*)d_in[8];
    const float* bo = (const float*)d_in[9];
    const float* qg = (const float*)d_in[10];
    const float* qb = (const float*)d_in[11];
    const float* kg = (const float*)d_in[12];
    const float* kb = (const float*)d_in[13];

    // ws layout (bf16 elements)
    unsigned short* xb = (unsigned short*)d_ws;                 // [8192][512]
    unsigned short* Wb = xb + (size_t)M_ * D_;                  // [4][512][512] q,k,v,o
    unsigned short* Y  = Wb + (size_t)4 * D_ * D_;              // [3][8192][512]
    unsigned short* AO = Y  + (size_t)3 * M_ * D_;              // [8192][512]
    float* out = (float*)d_out;

    // fp32 -> bf16 conversions
    cvt_x<<<dim3(M_ * D_ / 1024), dim3(256), 0, stream>>>(x, xb);
    cvt_w<<<dim3(D_ * D_ / 1024, 4), dim3(256), 0, stream>>>(Wq, Wk, Wv, Wo, Wb);

    // QKV projection: Y[0]=q, Y[1]=k, Y[2]=v
    gemm_nt<false><<<dim3(64, 12), dim3(256), 0, stream>>>(
        xb, Wb, bq, bk, bv, Y, nullptr);

    // per-head LayerNorm on q,k (in place)
    ln_qk<<<dim3(M_ * H_ / 4), dim3(256), 0, stream>>>(
        Y, Y + (size_t)M_ * D_, qg, qb, kg, kb);

    // attention
    attn_kernel<<<dim3(H_, N_ / 64, B_), dim3(256), 0, stream>>>(
        Y, Y + (size_t)M_ * D_, Y + (size_t)2 * M_ * D_, ab, AO);

    // output projection -> d_out (fp32)
    gemm_nt<true><<<dim3(64, 4), dim3(256), 0, stream>>>(
        AO, Wb + (size_t)3 * D_ * D_, bo, bo, bo, nullptr, out);
}

// Round 3
// 348.515 us; speedup vs baseline: 1.0222x; 1.0222x over previous
//
#include <hip/hip_runtime.h>

typedef __attribute__((ext_vector_type(8))) short short8;
typedef __attribute__((ext_vector_type(4))) float f32x4;
typedef __attribute__((ext_vector_type(4))) int i32x4;
typedef __attribute__((ext_vector_type(4))) unsigned short u16x4;

#define B_  4
#define N_  2048
#define D_  512
#define H_  8
#define DH_ 64
#define M_  (B_ * N_)   // 8192

__device__ __forceinline__ float bf2f(unsigned short s) {
    union { unsigned u; float f; } un; un.u = ((unsigned)s) << 16; return un.f;
}
__device__ __forceinline__ unsigned short f2bf(float f) {
    union { float f; unsigned u; } un; un.f = f;
    unsigned r = un.u + 0x7FFFu + ((un.u >> 16) & 1u);
    return (unsigned short)(r >> 16);
}

// ---------------------------------------------------------------------------
// fp32 -> bf16 conversion
// ---------------------------------------------------------------------------
__global__ __launch_bounds__(256) void cvt_x(const float* __restrict__ src,
                                             unsigned short* __restrict__ dst) {
    const int i = (blockIdx.x * 256 + threadIdx.x) * 4;
    f32x4 v = *(const f32x4*)(src + i);
    u16x4 o;
    o[0] = f2bf(v[0]); o[1] = f2bf(v[1]); o[2] = f2bf(v[2]); o[3] = f2bf(v[3]);
    *(u16x4*)(dst + i) = o;
}

__global__ __launch_bounds__(256) void cvt_w(const float* __restrict__ W0,
                                             const float* __restrict__ W1,
                                             const float* __restrict__ W2,
                                             const float* __restrict__ W3,
                                             unsigned short* __restrict__ dst) {
    const int sel = blockIdx.y;
    const float* src = (sel == 0) ? W0 : (sel == 1) ? W1 : (sel == 2) ? W2 : W3;
    unsigned short* d = dst + (size_t)sel * D_ * D_;
    const int i = (blockIdx.x * 256 + threadIdx.x) * 4;
    f32x4 v = *(const f32x4*)(src + i);
    u16x4 o;
    o[0] = f2bf(v[0]); o[1] = f2bf(v[1]); o[2] = f2bf(v[2]); o[3] = f2bf(v[3]);
    *(u16x4*)(d + i) = o;
}

// ---------------------------------------------------------------------------
// NT GEMM: out[m][n] = sum_k A[m][k]*W[n][k] + bias[n]; optional fused
// per-head LayerNorm (LNF, sel<2) over 64-col head groups.
// Tile 128x128, BK=32, 4 waves, 16x16x32 bf16 MFMA.
// ---------------------------------------------------------------------------
template <bool F32OUT, bool LNF>
__global__ __launch_bounds__(256) void gemm_nt(
    const unsigned short* __restrict__ A,
    const unsigned short* __restrict__ W,     // [nsel][512][512]
    const float* __restrict__ Bv0,
    const float* __restrict__ Bv1,
    const float* __restrict__ Bv2,
    const float* __restrict__ g0, const float* __restrict__ be0,
    const float* __restrict__ g1, const float* __restrict__ be1,
    unsigned short* __restrict__ outb,
    float* __restrict__ outf)
{
    const int mt = blockIdx.x;
    const int nt = blockIdx.y;
    const int sel = nt >> 2;
    const unsigned short* Wp = W + (size_t)sel * D_ * D_;
    const float* Bv = (sel == 0) ? Bv0 : (sel == 1) ? Bv1 : Bv2;
    const int n0 = (nt & 3) * 128;

    __shared__ __align__(16) unsigned short As[128][48];
    __shared__ __align__(16) unsigned short Bs[128][48];

    const int tid = threadIdx.x;
    const int w   = tid >> 6;
    const int l   = tid & 63;
    const int l15 = l & 15;
    const int qd  = l >> 4;
    const int wr  = w >> 1;
    const int wc  = w & 1;

    f32x4 acc[4][4];
#pragma unroll
    for (int i = 0; i < 4; ++i)
#pragma unroll
        for (int j = 0; j < 4; ++j)
            acc[i][j] = (f32x4){0.f, 0.f, 0.f, 0.f};

    const int c0 = tid, c1 = tid + 256;
    const int r0 = c0 >> 2, o0 = (c0 & 3) << 3;
    const int r1 = c1 >> 2, o1 = (c1 & 3) << 3;

    for (int k0 = 0; k0 < D_; k0 += 32) {
        __syncthreads();
        *(i32x4*)&As[r0][o0] = *(const i32x4*)(A  + (size_t)(mt * 128 + r0) * D_ + k0 + o0);
        *(i32x4*)&Bs[r0][o0] = *(const i32x4*)(Wp + (size_t)(n0 + r0) * D_ + k0 + o0);
        *(i32x4*)&As[r1][o1] = *(const i32x4*)(A  + (size_t)(mt * 128 + r1) * D_ + k0 + o1);
        *(i32x4*)&Bs[r1][o1] = *(const i32x4*)(Wp + (size_t)(n0 + r1) * D_ + k0 + o1);
        __syncthreads();

        short8 af[4], bf[4];
#pragma unroll
        for (int rt = 0; rt < 4; ++rt)
            af[rt] = *(const short8*)&As[wr * 64 + rt * 16 + l15][qd * 8];
#pragma unroll
        for (int ct = 0; ct < 4; ++ct)
            bf[ct] = *(const short8*)&Bs[wc * 64 + ct * 16 + l15][qd * 8];
#pragma unroll
        for (int rt = 0; rt < 4; ++rt)
#pragma unroll
            for (int ct = 0; ct < 4; ++ct)
                acc[rt][ct] = __builtin_amdgcn_mfma_f32_16x16x32_bf16(
                    af[rt], bf[ct], acc[rt][ct], 0, 0, 0);
    }

    // epilogue: bias (+ optional fused per-head LN), write
    const float* gam = (sel == 0) ? g0 : g1;
    const float* bet = (sel == 0) ? be0 : be1;
    float gv[4], bv2[4];
    if (LNF) {
#pragma unroll
        for (int ct = 0; ct < 4; ++ct) { gv[ct] = gam[ct * 16 + l15]; bv2[ct] = bet[ct * 16 + l15]; }
    }

#pragma unroll
    for (int rt = 0; rt < 4; ++rt) {
        float v[4][4];   // [ct][r]
#pragma unroll
        for (int ct = 0; ct < 4; ++ct) {
            const float bias = Bv[n0 + wc * 64 + ct * 16 + l15];
#pragma unroll
            for (int r = 0; r < 4; ++r) v[ct][r] = acc[rt][ct][r] + bias;
        }
        if (LNF && sel < 2) {
#pragma unroll
            for (int r = 0; r < 4; ++r) {
                float s  = v[0][r] + v[1][r] + v[2][r] + v[3][r];
                float s2 = v[0][r]*v[0][r] + v[1][r]*v[1][r] + v[2][r]*v[2][r] + v[3][r]*v[3][r];
#pragma unroll
                for (int o = 1; o <= 8; o <<= 1) {
                    s  += __shfl_xor(s, o);
                    s2 += __shfl_xor(s2, o);
                }
                const float mu  = s * 0.015625f;
                const float var = s2 * 0.015625f - mu * mu;
                const float rs  = rsqrtf(var + 1e-6f);
#pragma unroll
                for (int ct = 0; ct < 4; ++ct)
                    v[ct][r] = (v[ct][r] - mu) * rs * gv[ct] + bv2[ct];
            }
        }
#pragma unroll
        for (int ct = 0; ct < 4; ++ct) {
            const int col  = n0 + wc * 64 + ct * 16 + l15;
            const int row0 = mt * 128 + wr * 64 + rt * 16 + qd * 4;
#pragma unroll
            for (int r = 0; r < 4; ++r) {
                const size_t oidx = (size_t)(row0 + r) * D_ + col;
                if (F32OUT) outf[oidx] = v[ct][r];
                else        outb[(size_t)sel * M_ * D_ + oidx] = f2bf(v[ct][r]);
            }
        }
    }
}

// ---------------------------------------------------------------------------
// V transpose: V[b*2048+n][dh512] -> Vt[b][dh512][n2048]
// ---------------------------------------------------------------------------
__global__ __launch_bounds__(256) void transpose_v(
    const unsigned short* __restrict__ V, unsigned short* __restrict__ Vt)
{
    const int nt = blockIdx.x;   // 0..31 (n tiles of 64)
    const int dt = blockIdx.y;   // 0..7  (dh tiles of 64)
    const int b  = blockIdx.z;
    __shared__ __align__(16) unsigned short T[64][72];
    const int t = threadIdx.x;

#pragma unroll
    for (int half = 0; half < 2; ++half) {
        const int n = half * 32 + (t >> 3);
        const int c = (t & 7) * 8;
        short8 v = *(const short8*)(V + (size_t)(b * N_ + nt * 64 + n) * D_ + dt * 64 + c);
#pragma unroll
        for (int j = 0; j < 8; ++j) T[c + j][n] = (unsigned short)v[j];
    }
    __syncthreads();
    const int dh = t >> 2, p = t & 3;
    i32x4 a0 = *(const i32x4*)&T[dh][p * 16];
    i32x4 a1 = *(const i32x4*)&T[dh][p * 16 + 8];
    unsigned short* dst = Vt + ((size_t)b * D_ + dt * 64 + dh) * N_ + nt * 64 + p * 16;
    *(i32x4*)dst       = a0;
    *(i32x4*)(dst + 8) = a1;
}

// ---------------------------------------------------------------------------
// Attention v2: one wave = one head, 32 q-rows; S^T = K Q^T, O^T = V^T P^T.
// All operands from global (L1/L2); P via per-wave LDS; NO barriers.
// ---------------------------------------------------------------------------
__global__ __launch_bounds__(256) void attn2(
    const unsigned short* __restrict__ Qm,
    const unsigned short* __restrict__ Km,
    const unsigned short* __restrict__ Vt,
    const float* __restrict__ bias,
    unsigned short* __restrict__ AO)
{
    const int hg = blockIdx.x;   // 0..1
    const int qt = blockIdx.y;   // 0..63
    const int b  = blockIdx.z;   // 0..3
    const int w  = threadIdx.x >> 6;
    const int h  = hg * 4 + w;
    const int l  = threadIdx.x & 63;
    const int l15 = l & 15;
    const int qd  = l >> 4;
    const int q0 = qt * 32;

    __shared__ __align__(16) unsigned short Pw[4][32][40];

    // Q fragments (B-operand): n=q (l15), k=dh (hf*32+qd*8+j)
    short8 qf[2][2];
#pragma unroll
    for (int ct = 0; ct < 2; ++ct)
#pragma unroll
        for (int hf = 0; hf < 2; ++hf)
            qf[ct][hf] = *(const short8*)(Qm +
                (size_t)(b * N_ + q0 + ct * 16 + l15) * D_ + h * DH_ + hf * 32 + qd * 8);

    f32x4 Ot[4][2];
#pragma unroll
    for (int rt = 0; rt < 4; ++rt)
#pragma unroll
        for (int ct = 0; ct < 2; ++ct) Ot[rt][ct] = (f32x4){0.f, 0.f, 0.f, 0.f};
    float m_i[2] = {-3.0e38f, -3.0e38f};
    float l_i[2] = {0.f, 0.f};

    const unsigned short* kb_ = Km + (size_t)b * N_ * D_ + h * DH_;
    const unsigned short* vb_ = Vt + ((size_t)b * D_ + h * DH_) * N_;
    const float* bb_ = bias + (size_t)b * N_ * N_ + (size_t)q0 * N_;

    for (int kt = 0; kt < N_ / 32; ++kt) {
        const int kv0 = kt * 32;

        // K fragments (A-operand): m=kv (l15), k=dh
        short8 kf[2][2];
#pragma unroll
        for (int rt = 0; rt < 2; ++rt)
#pragma unroll
            for (int hf = 0; hf < 2; ++hf)
                kf[rt][hf] = *(const short8*)(kb_ +
                    (size_t)(kv0 + rt * 16 + l15) * D_ + hf * 32 + qd * 8);

        // S^T = K Q^T : C row=kv(qd*4+r), col=q(l15)
        f32x4 St[2][2];
#pragma unroll
        for (int rt = 0; rt < 2; ++rt)
#pragma unroll
            for (int ct = 0; ct < 2; ++ct) {
                f32x4 s = (f32x4){0.f, 0.f, 0.f, 0.f};
                s = __builtin_amdgcn_mfma_f32_16x16x32_bf16(kf[rt][0], qf[ct][0], s, 0, 0, 0);
                s = __builtin_amdgcn_mfma_f32_16x16x32_bf16(kf[rt][1], qf[ct][1], s, 0, 0, 0);
                St[rt][ct] = s;
            }

        // bias fragments: float4 over 4 consecutive kv
        f32x4 bf4[2][2];
#pragma unroll
        for (int rt = 0; rt < 2; ++rt)
#pragma unroll
            for (int ct = 0; ct < 2; ++ct)
                bf4[rt][ct] = *(const f32x4*)(bb_ +
                    (size_t)(ct * 16 + l15) * N_ + kv0 + rt * 16 + qd * 4);

        // online softmax (per lane: q fixed = ct*16+l15; kv across rt,qd,r)
#pragma unroll
        for (int ct = 0; ct < 2; ++ct) {
            float sv[2][4];
            float mx = -3.0e38f;
#pragma unroll
            for (int rt = 0; rt < 2; ++rt)
#pragma unroll
                for (int r = 0; r < 4; ++r) {
                    const float x = St[rt][ct][r] * 0.125f + bf4[rt][ct][r];
                    sv[rt][r] = x;
                    mx = fmaxf(mx, x);
                }
            mx = fmaxf(mx, __shfl_xor(mx, 16));
            mx = fmaxf(mx, __shfl_xor(mx, 32));
            const float mnew  = fmaxf(m_i[ct], mx);
            const float alpha = __expf(m_i[ct] - mnew);
            float rsum = 0.f;
#pragma unroll
            for (int rt = 0; rt < 2; ++rt) {
                u16x4 pb;
#pragma unroll
                for (int r = 0; r < 4; ++r) {
                    const float p = __expf(sv[rt][r] - mnew);
                    rsum += p;
                    pb[r] = f2bf(p);
                }
                *(u16x4*)&Pw[w][ct * 16 + l15][rt * 16 + qd * 4] = pb;  // 8B, 4 consecutive kv
            }
            rsum += __shfl_xor(rsum, 16);
            rsum += __shfl_xor(rsum, 32);
            l_i[ct] = l_i[ct] * alpha + rsum;
            m_i[ct] = mnew;
#pragma unroll
            for (int rt = 0; rt < 4; ++rt)
#pragma unroll
                for (int r = 0; r < 4; ++r) Ot[rt][ct][r] *= alpha;
        }

        // O^T += V^T P^T
        short8 vf[4];
#pragma unroll
        for (int rt = 0; rt < 4; ++rt)
            vf[rt] = *(const short8*)(vb_ + (size_t)(rt * 16 + l15) * N_ + kv0 + qd * 8);
        short8 pf[2];
#pragma unroll
        for (int ct = 0; ct < 2; ++ct)
            pf[ct] = *(const short8*)&Pw[w][ct * 16 + l15][qd * 8];
#pragma unroll
        for (int rt = 0; rt < 4; ++rt)
#pragma unroll
            for (int ct = 0; ct < 2; ++ct)
                Ot[rt][ct] = __builtin_amdgcn_mfma_f32_16x16x32_bf16(
                    vf[rt], pf[ct], Ot[rt][ct], 0, 0, 0);
    }

    // epilogue: O^T frag: row=dh(rt*16+qd*4+r), col=q(ct*16+l15)
#pragma unroll
    for (int ct = 0; ct < 2; ++ct) {
        const float inv = 1.f / l_i[ct];
        const int q = q0 + ct * 16 + l15;
#pragma unroll
        for (int rt = 0; rt < 4; ++rt) {
            u16x4 ob;
#pragma unroll
            for (int r = 0; r < 4; ++r) ob[r] = f2bf(Ot[rt][ct][r] * inv);
            *(u16x4*)(AO + (size_t)(b * N_ + q) * D_ + h * DH_ + rt * 16 + qd * 4) = ob;
        }
    }
}

// ---------------------------------------------------------------------------
extern "C" void kernel_launch(void* const* d_in, const int* in_sizes, int n_in,
                              void* d_out, int out_size, void* d_ws, size_t ws_size,
                              hipStream_t stream) {
    const float* x  = (const float*)d_in[0];
    const float* ab = (const float*)d_in[1];
    const float* Wq = (const float*)d_in[2];
    const float* bq = (const float*)d_in[3];
    const float* Wk = (const float*)d_in[4];
    const float* bk = (const float*)d_in[5];
    const float* Wv = (const float*)d_in[6];
    const float* bv = (const float*)d_in[7];
    const float* Wo = (const float*)d_in[8];
    const float* bo = (const float*)d_in[9];
    const float* qg = (const float*)d_in[10];
    const float* qb = (const float*)d_in[11];
    const float* kg = (const float*)d_in[12];
    const float* kb = (const float*)d_in[13];

    // ws layout (bf16 elements)
    unsigned short* xb = (unsigned short*)d_ws;                 // [8192][512]
    unsigned short* Wb = xb + (size_t)M_ * D_;                  // [4][512][512] q,k,v,o
    unsigned short* Y  = Wb + (size_t)4 * D_ * D_;              // [3][8192][512]
    unsigned short* Vt = Y  + (size_t)3 * M_ * D_;              // [4][512][2048]
    unsigned short* AO = Vt + (size_t)M_ * D_;                  // [8192][512]
    float* out = (float*)d_out;

    cvt_x<<<dim3(M_ * D_ / 1024), dim3(256), 0, stream>>>(x, xb);
    cvt_w<<<dim3(D_ * D_ / 1024, 4), dim3(256), 0, stream>>>(Wq, Wk, Wv, Wo, Wb);

    // QKV projection with fused per-head LN on q,k
    gemm_nt<false, true><<<dim3(64, 12), dim3(256), 0, stream>>>(
        xb, Wb, bq, bk, bv, qg, qb, kg, kb, Y, nullptr);

    // V -> V^T
    transpose_v<<<dim3(32, 8, 4), dim3(256), 0, stream>>>(
        Y + (size_t)2 * M_ * D_, Vt);

    // attention
    attn2<<<dim3(2, 64, 4), dim3(256), 0, stream>>>(
        Y, Y + (size_t)M_ * D_, Vt, ab, AO);

    // output projection -> d_out (fp32)
    gemm_nt<true, false><<<dim3(64, 4), dim3(256), 0, stream>>>(
        AO, Wb + (size_t)3 * D_ * D_, bo, bo, bo,
        nullptr, nullptr, nullptr, nullptr, nullptr, out);
}